// Round 6
// baseline (747.465 us; speedup 1.0000x reference)
//
#include <hip/hip_runtime.h>

// Problem constants
constexpr int NN  = 131072;   // nodes
constexpr int NE  = 2097152;  // edges
constexpr int HD  = 128;      // hidden
constexpr int NG  = 8192;     // graphs
constexpr int NA  = 28;       // atom types
constexpr int NL  = 4;        // layers

// CSR bucketing
constexpr int NB   = 256;     // buckets
constexpr int BSH  = 9;       // dst>>9 -> bucket (512 nodes/bucket)
constexpr int BNOD = 512;     // nodes per bucket
constexpr int CAP  = 10240;   // slots per bucket (mean 8192 + 22 sigma)

// ---------------- workspace layout (bytes) ----------------
constexpr size_t SZ_FB   = (size_t)NN * HD * 2;          // 32 MiB bf16 feature buf
constexpr size_t OFF_XB   = 0;
constexpr size_t OFF_YB   = OFF_XB + SZ_FB;
constexpr size_t OFF_ESRC = OFF_YB + SZ_FB;
constexpr size_t OFF_DEG  = OFF_ESRC + (size_t)NE * 4;
constexpr size_t OFF_GCNT = OFF_DEG + (size_t)NN * 4;
constexpr size_t OFF_ROW  = OFF_GCNT + (size_t)NG * 4;
constexpr size_t OFF_IDEG = OFF_ROW + (size_t)NN * 4;
constexpr size_t OFF_IGC  = OFF_IDEG + (size_t)NN * 4;
constexpr size_t OFF_BSUM = OFF_IGC + (size_t)NG * 4;
constexpr size_t OFF_COFF = OFF_BSUM + 512;
constexpr size_t OFF_WC   = OFF_COFF + 512;
constexpr size_t OFF_WNT  = OFF_WC + 512;                // bf16 W transposed [L][128][256]
constexpr size_t OFF_EBUF = OFF_WNT + (size_t)NL * HD * 256 * 2;
constexpr size_t OFF_GCUR = OFF_EBUF + (size_t)NB * CAP * 4;
constexpr size_t OFF_WET  = OFF_GCUR + (size_t)NB * 4;   // bf16 W_emb^T [128][32]

// ---------------- bf16 helpers ----------------
__device__ __forceinline__ float blo(uint x) { return __uint_as_float(x << 16); }
__device__ __forceinline__ float bhi(uint x) { return __uint_as_float(x & 0xFFFF0000u); }
__device__ __forceinline__ unsigned short f2b(float f) {
  uint u = __float_as_uint(f);
  return (unsigned short)((u + 0x7FFFu + ((u >> 16) & 1u)) >> 16);
}
__device__ __forceinline__ uint pack2(float a, float b) {
  uint ua = __float_as_uint(a), ub = __float_as_uint(b);
  uint lo = (ua + 0x7FFFu + ((ua >> 16) & 1u)) >> 16;
  uint hi = (ub + 0x7FFFu + ((ub >> 16) & 1u)) & 0xFFFF0000u;
  return lo | hi;
}

typedef __attribute__((ext_vector_type(8))) short bf16x8;
typedef __attribute__((ext_vector_type(4))) float f32x4;

// ---------------- CSR build: bucketed ----------------
__global__ void k_binit(int* __restrict__ gcur) {
  int b = threadIdx.x;           // 256
  gcur[b] = b * CAP;
}

// partition edges into NB buckets by dst>>BSH; packed = (dst&511)<<17 | src
__global__ __launch_bounds__(256) void k_bin(const int* __restrict__ src,
                                             const int* __restrict__ dst,
                                             int* __restrict__ gcur,
                                             uint* __restrict__ ebuf) {
  __shared__ int cnt[NB];
  __shared__ int gbase[NB];
  int t = threadIdx.x;
  cnt[t] = 0;
  int es[16], ed[16];
  int base = blockIdx.x * 4096 + t;
#pragma unroll
  for (int j = 0; j < 16; j++) {
    es[j] = src[base + j * 256];
    ed[j] = dst[base + j * 256];
  }
  __syncthreads();
#pragma unroll
  for (int j = 0; j < 16; j++) atomicAdd(&cnt[ed[j] >> BSH], 1);
  __syncthreads();
  int c = cnt[t];
  if (c > 0) gbase[t] = atomicAdd(&gcur[t], c);
  cnt[t] = 0;
  __syncthreads();
#pragma unroll
  for (int j = 0; j < 16; j++) {
    int b = ed[j] >> BSH;
    int r = atomicAdd(&cnt[b], 1);
    ebuf[(size_t)gbase[b] + r] = ((uint)(ed[j] & (BNOD - 1)) << 17) | (uint)es[j];
  }
}

// per-bucket degree histogram (LDS), coalesced deg writes, no global atomics
__global__ __launch_bounds__(256) void k_deg(const int* __restrict__ gcur,
                                             const uint* __restrict__ ebuf,
                                             int* __restrict__ deg) {
  __shared__ int h[BNOD];
  int b = blockIdx.x, t = threadIdx.x;
  h[t] = 0; h[t + 256] = 0;
  int n = gcur[b] - b * CAP;
  __syncthreads();
  const uint* eb = ebuf + (size_t)b * CAP;
  for (int i = t; i < n; i += 256) atomicAdd(&h[eb[i] >> 17], 1);
  __syncthreads();
  deg[b * BNOD + t] = h[t];
  deg[b * BNOD + t + 256] = h[t + 256];
}

__global__ void k_scan1(const int* __restrict__ deg, int* __restrict__ bsum) {
  __shared__ int s[256];
  int b = blockIdx.x, t = threadIdx.x;
  const int4* p = (const int4*)(deg + (size_t)b * 1024);
  int4 v = p[t];
  s[t] = v.x + v.y + v.z + v.w;
  __syncthreads();
  for (int o = 128; o > 0; o >>= 1) {
    if (t < o) s[t] += s[t + o];
    __syncthreads();
  }
  if (t == 0) bsum[b] = s[0];
}

__global__ void k_scan2(const int* __restrict__ bsum, int* __restrict__ coff) {
  __shared__ int s[128];
  int t = threadIdx.x;
  int mine = bsum[t];
  s[t] = mine;
  __syncthreads();
  for (int o = 1; o < 128; o <<= 1) {
    int v = (t >= o) ? s[t - o] : 0;
    __syncthreads();
    s[t] += v;
    __syncthreads();
  }
  coff[t] = s[t] - mine;  // exclusive
}

__global__ void k_scan3(const int* __restrict__ deg, const int* __restrict__ coff,
                        int* __restrict__ row_start, float* __restrict__ inv_deg) {
  __shared__ int s[256];
  int b = blockIdx.x, t = threadIdx.x;
  int base = b * 1024 + t * 4;
  const int4* p = (const int4*)(deg + base);
  int4 d = *p;
  int lsum = d.x + d.y + d.z + d.w;
  s[t] = lsum;
  __syncthreads();
  for (int o = 1; o < 256; o <<= 1) {
    int v = (t >= o) ? s[t - o] : 0;
    __syncthreads();
    s[t] += v;
    __syncthreads();
  }
  int pre = coff[b] + s[t] - lsum;
  int r0 = pre, r1 = r0 + d.x, r2 = r1 + d.y, r3 = r2 + d.z;
  row_start[base] = r0;  row_start[base + 1] = r1;
  row_start[base + 2] = r2;  row_start[base + 3] = r3;
  inv_deg[base]     = 1.0f / fmaxf((float)d.x, 1.0f);
  inv_deg[base + 1] = 1.0f / fmaxf((float)d.y, 1.0f);
  inv_deg[base + 2] = 1.0f / fmaxf((float)d.z, 1.0f);
  inv_deg[base + 3] = 1.0f / fmaxf((float)d.w, 1.0f);
}

// per-bucket placement: LDS cursors, esrc writes land in a 32KB window
__global__ __launch_bounds__(256) void k_place2(const int* __restrict__ gcur,
                                                const uint* __restrict__ ebuf,
                                                const int* __restrict__ row_start,
                                                int* __restrict__ esrc) {
  __shared__ int cur[BNOD];
  int b = blockIdx.x, t = threadIdx.x;
  cur[t] = row_start[b * BNOD + t];
  cur[t + 256] = row_start[b * BNOD + t + 256];
  int n = gcur[b] - b * CAP;
  __syncthreads();
  const uint* eb = ebuf + (size_t)b * CAP;
  for (int i = t; i < n; i += 256) {
    uint p = eb[i];
    int r = atomicAdd(&cur[p >> 17], 1);
    esrc[r] = (int)(p & 0x1FFFFu);
  }
}

__global__ void k_ghist(const int* __restrict__ gid, int* __restrict__ gcnt) {
  int i = blockIdx.x * blockDim.x + threadIdx.x;
  if (i < NN) atomicAdd(&gcnt[gid[i]], 1);
}

__global__ void k_ginit(const int* __restrict__ gcnt, float* __restrict__ inv_gcnt,
                        float* __restrict__ out, const float* __restrict__ b_pred) {
  int g = blockIdx.x * blockDim.x + threadIdx.x;
  if (g < NG) {
    inv_gcnt[g] = 1.0f / fmaxf((float)gcnt[g], 1.0f);
    out[g] = b_pred[0];
  }
}

// ---------------- weight prep ----------------
// Wnt[l][c][k] = bf16(W_node[l][k][c])
__global__ void k_wprep(const float* __restrict__ Wn, unsigned short* __restrict__ Wnt) {
  int i = blockIdx.x * 256 + threadIdx.x;   // L*256*128 total
  int l = i >> 15;
  int k = (i >> 7) & 255;
  int c = i & 127;
  float v = Wn[((size_t)l * 256 + k) * HD + c];
  Wnt[((size_t)l * HD + c) * 256 + k] = f2b(v);
}

// Wet[c][k] = bf16(W_emb[k][c]), k padded 28->32 with zeros
__global__ void k_weprep(const float* __restrict__ We, unsigned short* __restrict__ Wet) {
  int i = blockIdx.x * 256 + threadIdx.x;   // 128*32 = 4096 total
  int col = i >> 5, k = i & 31;
  Wet[i] = (k < NA) ? f2b(We[(size_t)k * HD + col]) : (unsigned short)0;
}

// ---------------- embedding (MFMA): Xb = bf16(h @ W_emb) ----------------
// block: 64 rows x 128 cols, 4 waves 2x2; K=32 (padded from 28)
__global__ __launch_bounds__(256) void k_embed(const float* __restrict__ h,
                                               const unsigned short* __restrict__ Wet,
                                               unsigned short* __restrict__ Xb) {
  int t = threadIdx.x;
  int lane = t & 63, w = t >> 6;
  int wr = w >> 1, wc = w & 1;
  int row0 = blockIdx.x * 64 + wr * 32;
  int col0 = wc * 64;
  int fr = lane & 15;
  int fk = (lane >> 4) * 8;

  f32x4 acc[2][4] = {};
  bf16x8 a[2];
#pragma unroll
  for (int rt = 0; rt < 2; rt++) {
    int row = row0 + rt * 16 + fr;
    const float* hp = h + (size_t)row * NA + fk;
    float4 p = *(const float4*)hp;                    // k = fk..fk+3 (always < 28)
    float4 q = make_float4(0.f, 0.f, 0.f, 0.f);
    if (fk < 24) q = *(const float4*)(hp + 4);        // k = fk+4..fk+7; fk==24 -> pad 0
    a[rt][0] = (short)f2b(p.x); a[rt][1] = (short)f2b(p.y);
    a[rt][2] = (short)f2b(p.z); a[rt][3] = (short)f2b(p.w);
    a[rt][4] = (short)f2b(q.x); a[rt][5] = (short)f2b(q.y);
    a[rt][6] = (short)f2b(q.z); a[rt][7] = (short)f2b(q.w);
  }
#pragma unroll
  for (int ct = 0; ct < 4; ct++) {
    int col = col0 + ct * 16 + fr;
    bf16x8 b = *(const bf16x8*)(Wet + (size_t)col * 32 + fk);
#pragma unroll
    for (int rt = 0; rt < 2; rt++)
      acc[rt][ct] = __builtin_amdgcn_mfma_f32_16x16x32_bf16(a[rt], b, acc[rt][ct], 0, 0, 0);
  }
  int oc = lane & 15, orb = (lane >> 4) * 4;
#pragma unroll
  for (int rt = 0; rt < 2; rt++) {
#pragma unroll
    for (int ct = 0; ct < 4; ct++) {
      int col = col0 + ct * 16 + oc;
#pragma unroll
      for (int r = 0; r < 4; r++) {
        int row = row0 + rt * 16 + orb + r;
        Xb[(size_t)row * HD + col] = f2b(acc[rt][ct][r]);
      }
    }
  }
}

// ---------------- fully fused layer: reg-gather + MFMA + epilogue ----------------
// 4 waves/block, wave owns 16 rows (one A-frag tile). Lane (fr,fkg):
//  gather: c[row0+fr][32j + 8*fkg + i] accumulated in regs (4x uint4/edge/lane)
//  MFMA:   ks=0..3 A from Hb, ks=4..7 A = gathered c (already in frag layout)
//  epilogue: relu(+bias)*snorm + residual, shfl-paired uint stores
__global__ __launch_bounds__(256, 4) void k_fused(const unsigned short* __restrict__ Hb,
                                                  unsigned short* __restrict__ Ho,
                                                  const int* __restrict__ row_start,
                                                  const int* __restrict__ deg,
                                                  const int* __restrict__ esrc,
                                                  const float* __restrict__ inv_deg,
                                                  const unsigned short* __restrict__ Wt,
                                                  const float* __restrict__ bias,
                                                  const float* __restrict__ snorm) {
  int t = threadIdx.x;
  int lane = t & 63, w = t >> 6;
  int fr = lane & 15;            // row within wave tile / B-col within ct-tile
  int fkg = lane >> 4;           // k-chunk group 0..3
  int row0 = blockIdx.x * 64 + w * 16;
  int vrow = row0 + fr;

  // ---- gather into registers ----
  float ca[4][8] = {};           // [j: k-32-block][i: elem] for k = 32j + 8*fkg + i
  int rs = row_start[vrow];
  int d  = deg[vrow];
  int e = 0;
  for (; e + 2 <= d; e += 2) {
    int i0 = esrc[rs + e];
    int i1 = esrc[rs + e + 1];
    const uint4* p0 = (const uint4*)(Hb + (size_t)i0 * HD);
    const uint4* p1 = (const uint4*)(Hb + (size_t)i1 * HD);
    uint4 x0 = p0[fkg], x1 = p0[4 + fkg], x2 = p0[8 + fkg], x3 = p0[12 + fkg];
    uint4 y0 = p1[fkg], y1 = p1[4 + fkg], y2 = p1[8 + fkg], y3 = p1[12 + fkg];
#define ACC8(J, V)                                                        \
    ca[J][0] += blo(V.x); ca[J][1] += bhi(V.x);                           \
    ca[J][2] += blo(V.y); ca[J][3] += bhi(V.y);                           \
    ca[J][4] += blo(V.z); ca[J][5] += bhi(V.z);                           \
    ca[J][6] += blo(V.w); ca[J][7] += bhi(V.w);
    ACC8(0, x0) ACC8(1, x1) ACC8(2, x2) ACC8(3, x3)
    ACC8(0, y0) ACC8(1, y1) ACC8(2, y2) ACC8(3, y3)
  }
  if (e < d) {
    int i0 = esrc[rs + e];
    const uint4* p0 = (const uint4*)(Hb + (size_t)i0 * HD);
    uint4 x0 = p0[fkg], x1 = p0[4 + fkg], x2 = p0[8 + fkg], x3 = p0[12 + fkg];
    ACC8(0, x0) ACC8(1, x1) ACC8(2, x2) ACC8(3, x3)
  }
#undef ACC8

  // scale by 1/deg, pack to A-high fragments (already in MFMA A layout)
  float idg = inv_deg[vrow];
  bf16x8 ahi[4];
#pragma unroll
  for (int j = 0; j < 4; j++) {
    uint* u = (uint*)&ahi[j];
#pragma unroll
    for (int i = 0; i < 4; i++)
      u[i] = pack2(ca[j][2 * i] * idg, ca[j][2 * i + 1] * idg);
  }

  // ---- MFMA: wave tile 16 rows x 128 cols ----
  f32x4 acc[8] = {};
#pragma unroll
  for (int ks = 0; ks < 8; ks++) {
    bf16x8 a = (ks < 4)
        ? *(const bf16x8*)(Hb + (size_t)vrow * HD + ks * 32 + fkg * 8)
        : ahi[ks - 4];
#pragma unroll
    for (int ct = 0; ct < 8; ct++) {
      bf16x8 b = *(const bf16x8*)(Wt + (size_t)(ct * 16 + fr) * 256 + ks * 32 + fkg * 8);
      acc[ct] = __builtin_amdgcn_mfma_f32_16x16x32_bf16(a, b, acc[ct], 0, 0, 0);
    }
  }

  // ---- epilogue: relu(+bias)*snorm + residual; shfl-paired uint IO ----
  // acc layout: col = ct*16 + (lane&15), row = row0 + (lane>>4)*4 + r
#pragma unroll
  for (int r = 0; r < 4; r++) {
    int row = row0 + fkg * 4 + r;
    float sn = snorm[row];
#pragma unroll
    for (int ct = 0; ct < 8; ct++) {
      float v = acc[ct][r];
      float v2 = __shfl_xor(v, 1, 64);       // partner column value
      if (!(lane & 1)) {
        int col = ct * 16 + fr;              // fr even
        uint hp = *(const uint*)(Hb + (size_t)row * HD + col);
        float2 bv = *(const float2*)(bias + col);
        float o1 = fmaxf(v + bv.x, 0.f) * sn + blo(hp);
        float o2 = fmaxf(v2 + bv.y, 0.f) * sn + bhi(hp);
        *(uint*)(Ho + (size_t)row * HD + col) = pack2(o1, o2);
      }
    }
  }
}

// ---------------- readout ----------------
__global__ void k_wcombo(const float* __restrict__ W_ro, const float* __restrict__ W_pred,
                         float* __restrict__ wcv) {
  int i = threadIdx.x;  // 128
  float a = 0.f;
  for (int j = 0; j < HD; j++) a += W_ro[i * HD + j] * W_pred[j];
  wcv[i] = a;
}

__global__ void k_readout(const uint* __restrict__ H32, const float* __restrict__ wcv,
                          const int* __restrict__ gid, const float* __restrict__ inv_gcnt,
                          float* __restrict__ out) {
  int wave = threadIdx.x >> 6, lane = threadIdx.x & 63;
  int v = blockIdx.x * 4 + wave;
  uint x = H32[(size_t)v * 64 + lane];
  float2 wv = *(const float2*)(wcv + lane * 2);
  float p = blo(x) * wv.x + bhi(x) * wv.y;
#pragma unroll
  for (int o = 32; o > 0; o >>= 1) p += __shfl_down(p, o, 64);
  if (lane == 0) {
    int g = gid[v];
    atomicAdd(&out[g], p * inv_gcnt[g]);
  }
}

// ---------------- launch ----------------
extern "C" void kernel_launch(void* const* d_in, const int* in_sizes, int n_in,
                              void* d_out, int out_size, void* d_ws, size_t ws_size,
                              hipStream_t stream) {
  const float* h      = (const float*)d_in[0];
  const float* snorm  = (const float*)d_in[1];
  const float* W_emb  = (const float*)d_in[2];
  const float* W_node = (const float*)d_in[3];
  const float* b_node = (const float*)d_in[4];
  const float* W_ro   = (const float*)d_in[5];
  const float* W_pred = (const float*)d_in[6];
  const float* b_pred = (const float*)d_in[7];
  const int*   src    = (const int*)d_in[8];
  const int*   dst    = (const int*)d_in[9];
  const int*   gid    = (const int*)d_in[10];
  float* out = (float*)d_out;

  char* ws = (char*)d_ws;
  unsigned short* Xb   = (unsigned short*)(ws + OFF_XB);
  unsigned short* Yb   = (unsigned short*)(ws + OFF_YB);
  int*   esrc     = (int*)(ws + OFF_ESRC);
  int*   deg      = (int*)(ws + OFF_DEG);
  int*   gcnt     = (int*)(ws + OFF_GCNT);
  int*   row_s    = (int*)(ws + OFF_ROW);
  float* inv_deg  = (float*)(ws + OFF_IDEG);
  float* inv_gcnt = (float*)(ws + OFF_IGC);
  int*   bsum     = (int*)(ws + OFF_BSUM);
  int*   coff     = (int*)(ws + OFF_COFF);
  float* wcv      = (float*)(ws + OFF_WC);
  unsigned short* Wnt = (unsigned short*)(ws + OFF_WNT);
  uint*  ebuf     = (uint*)(ws + OFF_EBUF);
  int*   gcur     = (int*)(ws + OFF_GCUR);
  unsigned short* Wet = (unsigned short*)(ws + OFF_WET);

  hipMemsetAsync(ws + OFF_GCNT, 0, (size_t)NG * 4, stream);

  k_binit<<<1, NB, 0, stream>>>(gcur);
  k_bin<<<NE / 4096, 256, 0, stream>>>(src, dst, gcur, ebuf);
  k_deg<<<NB, 256, 0, stream>>>(gcur, ebuf, deg);
  k_scan1<<<NN / 1024, 256, 0, stream>>>(deg, bsum);
  k_scan2<<<1, 128, 0, stream>>>(bsum, coff);
  k_scan3<<<NN / 1024, 256, 0, stream>>>(deg, coff, row_s, inv_deg);
  k_place2<<<NB, 256, 0, stream>>>(gcur, ebuf, row_s, esrc);
  k_ghist<<<NN / 256, 256, 0, stream>>>(gid, gcnt);
  k_ginit<<<NG / 256, 256, 0, stream>>>(gcnt, inv_gcnt, out, b_pred);
  k_wprep<<<(NL * 256 * HD) / 256, 256, 0, stream>>>(W_node, Wnt);
  k_weprep<<<(HD * 32) / 256, 256, 0, stream>>>(W_emb, Wet);

  k_embed<<<NN / 64, 256, 0, stream>>>(h, Wet, Xb);

  for (int l = 0; l < NL; l++) {
    unsigned short* hb = (l & 1) ? Yb : Xb;
    unsigned short* ho = (l & 1) ? Xb : Yb;
    k_fused<<<NN / 64, 256, 0, stream>>>(hb, ho, row_s, deg, esrc, inv_deg,
                                         Wnt + (size_t)l * HD * 256,
                                         b_node + (size_t)l * HD, snorm);
  }
  // final h is in Xb after 4 layers (X->Y->X->Y->X)

  k_wcombo<<<1, 128, 0, stream>>>(W_ro, W_pred, wcv);
  k_readout<<<NN / 4, 256, 0, stream>>>((const uint*)Xb, wcv, gid, inv_gcnt, out);
}